// Round 1
// baseline (2898.506 us; speedup 1.0000x reference)
//
#include <hip/hip_runtime.h>

#define N_NODES 100000
#define N_EDGES 1600000

// ---------------------------------------------------------------------------
// K1: y = x @ W1  (N x 128 @ 128 x 64). Writes result to BOTH y (gather src)
// and z (accumulator, pre-initialized with the self term).
// Block: 256 threads -> 16 rows x 64 cols, W1 fully staged in LDS.
// ---------------------------------------------------------------------------
__global__ __launch_bounds__(256) void k_mm1(const float* __restrict__ x,
                                             const float* __restrict__ W1,
                                             float* __restrict__ y,
                                             float* __restrict__ z) {
    __shared__ float sW[128 * 64];   // 32 KB
    __shared__ float sx[16 * 132];   // padded stride 132 to break 4-way bank alias
    const int tid = threadIdx.x;
    for (int i = tid * 4; i < 128 * 64; i += 1024)
        *(float4*)&sW[i] = *(const float4*)&W1[i];
    const int row0 = blockIdx.x * 16;   // 6250 blocks * 16 = 100000 exact
    for (int i = tid * 4; i < 16 * 128; i += 1024) {
        int r = i >> 7, c = i & 127;
        *(float4*)&sx[r * 132 + c] = *(const float4*)&x[(size_t)(row0 + r) * 128 + c];
    }
    __syncthreads();
    const int r  = tid >> 4;          // 0..15
    const int c4 = (tid & 15) * 4;    // 0..60
    float4 acc = {0.f, 0.f, 0.f, 0.f};
    #pragma unroll 16
    for (int k = 0; k < 128; ++k) {
        float  xv = sx[r * 132 + k];
        float4 w  = *(float4*)&sW[k * 64 + c4];
        acc.x += xv * w.x; acc.y += xv * w.y; acc.z += xv * w.z; acc.w += xv * w.w;
    }
    size_t off = (size_t)(row0 + r) * 64 + c4;
    *(float4*)&y[off] = acc;
    *(float4*)&z[off] = acc;
}

// ---------------------------------------------------------------------------
// K2/K4: edge scatter: z[dst] += y[src], 64 ch. 16 threads/edge, float4 each.
// ---------------------------------------------------------------------------
__global__ __launch_bounds__(256) void k_scatter(const int* __restrict__ ei,
                                                 const float* __restrict__ y,
                                                 float* __restrict__ z) {
    const int t = blockIdx.x * 256 + threadIdx.x;
    const int e = t >> 4;
    if (e >= N_EDGES) return;
    const int c   = (t & 15) * 4;
    const int src = ei[e];
    const int dst = ei[N_EDGES + e];
    float4 v = *(const float4*)&y[(size_t)src * 64 + c];
    float* zp = &z[(size_t)dst * 64 + c];
    atomicAdd(zp + 0, v.x);
    atomicAdd(zp + 1, v.y);
    atomicAdd(zp + 2, v.z);
    atomicAdd(zp + 3, v.w);
}

// ---------------------------------------------------------------------------
// K3: h1 = relu(z1 + b1);  y2 = h1 @ W2  (64x64). Writes y2 to both y and z
// buffers (in-place over z1 rows — each block only touches its own 16 rows,
// reads complete before the post-__syncthreads writes).
// ---------------------------------------------------------------------------
__global__ __launch_bounds__(256) void k_relu_mm2(const float* __restrict__ z1,
                                                  const float* __restrict__ b1,
                                                  const float* __restrict__ W2,
                                                  float* __restrict__ y2,
                                                  float* __restrict__ z2) {
    __shared__ float sW[64 * 64];    // 16 KB
    __shared__ float sh[16 * 68];    // padded
    const int tid = threadIdx.x;
    for (int i = tid * 4; i < 64 * 64; i += 1024)
        *(float4*)&sW[i] = *(const float4*)&W2[i];
    const int row0 = blockIdx.x * 16;
    {
        int i = tid * 4;             // exactly 16*64 = 1024 floats
        int r = i >> 6, c = i & 63;
        float4 v  = *(const float4*)&z1[(size_t)(row0 + r) * 64 + c];
        float4 bb = *(const float4*)&b1[c];
        v.x = fmaxf(v.x + bb.x, 0.f);
        v.y = fmaxf(v.y + bb.y, 0.f);
        v.z = fmaxf(v.z + bb.z, 0.f);
        v.w = fmaxf(v.w + bb.w, 0.f);
        *(float4*)&sh[r * 68 + c] = v;
    }
    __syncthreads();
    const int r  = tid >> 4;
    const int c4 = (tid & 15) * 4;
    float4 acc = {0.f, 0.f, 0.f, 0.f};
    #pragma unroll 16
    for (int k = 0; k < 64; ++k) {
        float  hv = sh[r * 68 + k];
        float4 w  = *(float4*)&sW[k * 64 + c4];
        acc.x += hv * w.x; acc.y += hv * w.y; acc.z += hv * w.z; acc.w += hv * w.w;
    }
    size_t off = (size_t)(row0 + r) * 64 + c4;
    *(float4*)&y2[off] = acc;
    *(float4*)&z2[off] = acc;
}

// ---------------------------------------------------------------------------
// K5: per-node tail: h2 = relu(z2+b2); h3 = relu(h2@W3+b3); out = h3@W4+b4.
// One thread per node; W3/W4/b3 in LDS (broadcast reads, conflict-free).
// ---------------------------------------------------------------------------
__global__ __launch_bounds__(256) void k_tail(const float* __restrict__ z2,
                                              const float* __restrict__ b2,
                                              const float* __restrict__ W3,
                                              const float* __restrict__ b3,
                                              const float* __restrict__ W4,
                                              const float* __restrict__ b4,
                                              float* __restrict__ out) {
    __shared__ float sW3[64 * 16];   // 4 KB
    __shared__ float sW4[16];
    __shared__ float sb3[16];
    const int tid = threadIdx.x;
    *(float4*)&sW3[tid * 4] = *(const float4*)&W3[tid * 4];   // 1024 floats / 256 thr
    if (tid < 16) { sW4[tid] = W4[tid]; sb3[tid] = b3[tid]; }
    __syncthreads();
    const int node = blockIdx.x * 256 + tid;
    if (node >= N_NODES) return;

    float h[64];
    const float4* zp = (const float4*)&z2[(size_t)node * 64];
    #pragma unroll
    for (int i = 0; i < 16; ++i) {
        float4 v  = zp[i];
        float4 bb = *(const float4*)&b2[i * 4];
        h[i * 4 + 0] = fmaxf(v.x + bb.x, 0.f);
        h[i * 4 + 1] = fmaxf(v.y + bb.y, 0.f);
        h[i * 4 + 2] = fmaxf(v.z + bb.z, 0.f);
        h[i * 4 + 3] = fmaxf(v.w + bb.w, 0.f);
    }
    float acc[16];
    #pragma unroll
    for (int j = 0; j < 16; ++j) acc[j] = sb3[j];
    #pragma unroll 8
    for (int k = 0; k < 64; ++k) {
        float hv = h[k];
        #pragma unroll
        for (int j = 0; j < 16; ++j) acc[j] += hv * sW3[k * 16 + j];
    }
    float o = b4[0];
    #pragma unroll
    for (int j = 0; j < 16; ++j) o += fmaxf(acc[j], 0.f) * sW4[j];
    out[node] = o;
}

extern "C" void kernel_launch(void* const* d_in, const int* in_sizes, int n_in,
                              void* d_out, int out_size, void* d_ws, size_t ws_size,
                              hipStream_t stream) {
    const float* x  = (const float*)d_in[0];
    const int*   ei = (const int*)d_in[1];     // [2, E] int32
    const float* W1 = (const float*)d_in[2];
    const float* b1 = (const float*)d_in[3];
    const float* W2 = (const float*)d_in[4];
    const float* b2 = (const float*)d_in[5];
    const float* W3 = (const float*)d_in[6];
    const float* b3 = (const float*)d_in[7];
    const float* W4 = (const float*)d_in[8];
    const float* b4 = (const float*)d_in[9];
    float* out = (float*)d_out;

    float* bufA = (float*)d_ws;                       // y  (gather source)
    float* bufB = bufA + (size_t)N_NODES * 64;        // z  (accumulator)

    const int mmBlocks      = N_NODES / 16;           // 6250, exact
    const int scatterBlocks = (N_EDGES * 16) / 256;   // 100000, exact
    const int tailBlocks    = (N_NODES + 255) / 256;  // 391

    // conv1: y1 = x@W1 ; z1 = y1 + scatter(y1) ; h1 = relu(z1+b1)
    k_mm1<<<mmBlocks, 256, 0, stream>>>(x, W1, bufA, bufB);
    k_scatter<<<scatterBlocks, 256, 0, stream>>>(ei, bufA, bufB);
    // conv2: y2 = h1@W2 ; z2 = y2 + scatter(y2)
    k_relu_mm2<<<mmBlocks, 256, 0, stream>>>(bufB, b1, W2, bufA, bufB);
    k_scatter<<<scatterBlocks, 256, 0, stream>>>(ei, bufA, bufB);
    // head: relu(z2+b2) -> lin1+relu -> lin2
    k_tail<<<tailBlocks, 256, 0, stream>>>(bufB, b2, W3, b3, W4, b4, out);
}

// Round 2
// 598.006 us; speedup vs baseline: 4.8469x; 4.8469x over previous
//
#include <hip/hip_runtime.h>

#define N_NODES 100000
#define N_EDGES 1600000

// ---------------------------------------------------------------------------
// CSR build (rebuilt every launch; ws is re-poisoned between calls).
// ---------------------------------------------------------------------------
__global__ __launch_bounds__(1024) void k_zero(int* __restrict__ cnt) {
    int i = blockIdx.x * 1024 + threadIdx.x;
    if (i < N_NODES) cnt[i] = 0;
}

__global__ __launch_bounds__(256) void k_count(const int* __restrict__ ei,
                                               int* __restrict__ cnt) {
    int e = blockIdx.x * 256 + threadIdx.x;
    if (e < N_EDGES) atomicAdd(&cnt[ei[N_EDGES + e]], 1);
}

// Single-block exclusive scan of cnt[0..N) -> off[0..N]; also copies the
// exclusive offsets back into cnt[] to serve as permute cursors.
// Wave-shuffle scan + 16-entry LDS wave-sum scan: 2 barriers per 1024-tile.
__global__ __launch_bounds__(1024) void k_scan(int* __restrict__ cnt,
                                               int* __restrict__ off) {
    __shared__ int waveSums[16];
    const int tid    = threadIdx.x;
    const int lane   = tid & 63;
    const int waveId = tid >> 6;
    int carry = 0;                       // identical in every thread
    const int nTiles = (N_NODES + 1023) / 1024;
    for (int t = 0; t < nTiles; ++t) {
        int idx = t * 1024 + tid;
        int v = (idx < N_NODES) ? cnt[idx] : 0;
        int incl = v;
        #pragma unroll
        for (int s = 1; s < 64; s <<= 1) {
            int n = __shfl_up(incl, s, 64);
            if (lane >= s) incl += n;
        }
        if (lane == 63) waveSums[waveId] = incl;
        __syncthreads();
        int waveOff = 0, total = 0;
        #pragma unroll
        for (int w = 0; w < 16; ++w) {
            int ws = waveSums[w];
            waveOff += (w < waveId) ? ws : 0;
            total   += ws;
        }
        if (idx < N_NODES) {
            int o = carry + waveOff + incl - v;   // exclusive
            off[idx] = o;
            cnt[idx] = o;                          // cursor for permute
        }
        carry += total;
        __syncthreads();                           // protect waveSums reuse
    }
    if (tid == 0) off[N_NODES] = carry;            // == N_EDGES
}

__global__ __launch_bounds__(256) void k_permute(const int* __restrict__ ei,
                                                 int* __restrict__ cursor,
                                                 int* __restrict__ srcS) {
    int e = blockIdx.x * 256 + threadIdx.x;
    if (e >= N_EDGES) return;
    int src = ei[e];
    int dst = ei[N_EDGES + e];
    int pos = atomicAdd(&cursor[dst], 1);
    srcS[pos] = src;
}

// ---------------------------------------------------------------------------
// Gather-aggregate: z[n] = y[n] + sum_{e: dst==n} y[src_e].  One wave per
// node, lane == channel (64 ch). No atomics; y is LLC-resident (25.6 MB).
// ---------------------------------------------------------------------------
__global__ __launch_bounds__(256) void k_gather_agg(const int* __restrict__ off,
                                                    const int* __restrict__ srcS,
                                                    const float* __restrict__ y,
                                                    float* __restrict__ z) {
    const int node = blockIdx.x * 4 + (threadIdx.x >> 6);
    if (node >= N_NODES) return;
    const int lane = threadIdx.x & 63;
    const int beg = off[node];
    const int end = off[node + 1];
    float acc = y[(size_t)node * 64 + lane];
    int i = beg;
    for (; i + 4 <= end; i += 4) {       // 4-wide ILP: independent gathers
        int s0 = srcS[i], s1 = srcS[i + 1], s2 = srcS[i + 2], s3 = srcS[i + 3];
        float v0 = y[(size_t)s0 * 64 + lane];
        float v1 = y[(size_t)s1 * 64 + lane];
        float v2 = y[(size_t)s2 * 64 + lane];
        float v3 = y[(size_t)s3 * 64 + lane];
        acc += (v0 + v1) + (v2 + v3);
    }
    for (; i < end; ++i) acc += y[(size_t)srcS[i] * 64 + lane];
    z[(size_t)node * 64 + lane] = acc;
}

// ---------------------------------------------------------------------------
// K1: y = x @ W1  (N x 128 @ 128 x 64).
// ---------------------------------------------------------------------------
__global__ __launch_bounds__(256) void k_mm1(const float* __restrict__ x,
                                             const float* __restrict__ W1,
                                             float* __restrict__ y) {
    __shared__ float sW[128 * 64];   // 32 KB
    __shared__ float sx[16 * 132];
    const int tid = threadIdx.x;
    for (int i = tid * 4; i < 128 * 64; i += 1024)
        *(float4*)&sW[i] = *(const float4*)&W1[i];
    const int row0 = blockIdx.x * 16;
    for (int i = tid * 4; i < 16 * 128; i += 1024) {
        int r = i >> 7, c = i & 127;
        *(float4*)&sx[r * 132 + c] = *(const float4*)&x[(size_t)(row0 + r) * 128 + c];
    }
    __syncthreads();
    const int r  = tid >> 4;
    const int c4 = (tid & 15) * 4;
    float4 acc = {0.f, 0.f, 0.f, 0.f};
    #pragma unroll 16
    for (int k = 0; k < 128; ++k) {
        float  xv = sx[r * 132 + k];
        float4 w  = *(float4*)&sW[k * 64 + c4];
        acc.x += xv * w.x; acc.y += xv * w.y; acc.z += xv * w.z; acc.w += xv * w.w;
    }
    *(float4*)&y[(size_t)(row0 + r) * 64 + c4] = acc;
}

// ---------------------------------------------------------------------------
// K3: h1 = relu(z1 + b1);  y2 = h1 @ W2  (64x64).
// ---------------------------------------------------------------------------
__global__ __launch_bounds__(256) void k_relu_mm2(const float* __restrict__ z1,
                                                  const float* __restrict__ b1,
                                                  const float* __restrict__ W2,
                                                  float* __restrict__ y2) {
    __shared__ float sW[64 * 64];
    __shared__ float sh[16 * 68];
    const int tid = threadIdx.x;
    for (int i = tid * 4; i < 64 * 64; i += 1024)
        *(float4*)&sW[i] = *(const float4*)&W2[i];
    const int row0 = blockIdx.x * 16;
    {
        int i = tid * 4;
        int r = i >> 6, c = i & 63;
        float4 v  = *(const float4*)&z1[(size_t)(row0 + r) * 64 + c];
        float4 bb = *(const float4*)&b1[c];
        v.x = fmaxf(v.x + bb.x, 0.f);
        v.y = fmaxf(v.y + bb.y, 0.f);
        v.z = fmaxf(v.z + bb.z, 0.f);
        v.w = fmaxf(v.w + bb.w, 0.f);
        *(float4*)&sh[r * 68 + c] = v;
    }
    __syncthreads();
    const int r  = tid >> 4;
    const int c4 = (tid & 15) * 4;
    float4 acc = {0.f, 0.f, 0.f, 0.f};
    #pragma unroll 16
    for (int k = 0; k < 64; ++k) {
        float  hv = sh[r * 68 + k];
        float4 w  = *(float4*)&sW[k * 64 + c4];
        acc.x += hv * w.x; acc.y += hv * w.y; acc.z += hv * w.z; acc.w += hv * w.w;
    }
    *(float4*)&y2[(size_t)(row0 + r) * 64 + c4] = acc;
}

// ---------------------------------------------------------------------------
// K5: per-node tail: h2 = relu(z2+b2); h3 = relu(h2@W3+b3); out = h3@W4+b4.
// ---------------------------------------------------------------------------
__global__ __launch_bounds__(256) void k_tail(const float* __restrict__ z2,
                                              const float* __restrict__ b2,
                                              const float* __restrict__ W3,
                                              const float* __restrict__ b3,
                                              const float* __restrict__ W4,
                                              const float* __restrict__ b4,
                                              float* __restrict__ out) {
    __shared__ float sW3[64 * 16];
    __shared__ float sW4[16];
    __shared__ float sb3[16];
    const int tid = threadIdx.x;
    *(float4*)&sW3[tid * 4] = *(const float4*)&W3[tid * 4];
    if (tid < 16) { sW4[tid] = W4[tid]; sb3[tid] = b3[tid]; }
    __syncthreads();
    const int node = blockIdx.x * 256 + tid;
    if (node >= N_NODES) return;

    float h[64];
    const float4* zp = (const float4*)&z2[(size_t)node * 64];
    #pragma unroll
    for (int i = 0; i < 16; ++i) {
        float4 v  = zp[i];
        float4 bb = *(const float4*)&b2[i * 4];
        h[i * 4 + 0] = fmaxf(v.x + bb.x, 0.f);
        h[i * 4 + 1] = fmaxf(v.y + bb.y, 0.f);
        h[i * 4 + 2] = fmaxf(v.z + bb.z, 0.f);
        h[i * 4 + 3] = fmaxf(v.w + bb.w, 0.f);
    }
    float acc[16];
    #pragma unroll
    for (int j = 0; j < 16; ++j) acc[j] = sb3[j];
    #pragma unroll 8
    for (int k = 0; k < 64; ++k) {
        float hv = h[k];
        #pragma unroll
        for (int j = 0; j < 16; ++j) acc[j] += hv * sW3[k * 16 + j];
    }
    float o = b4[0];
    #pragma unroll
    for (int j = 0; j < 16; ++j) o += fmaxf(acc[j], 0.f) * sW4[j];
    out[node] = o;
}

extern "C" void kernel_launch(void* const* d_in, const int* in_sizes, int n_in,
                              void* d_out, int out_size, void* d_ws, size_t ws_size,
                              hipStream_t stream) {
    const float* x  = (const float*)d_in[0];
    const int*   ei = (const int*)d_in[1];
    const float* W1 = (const float*)d_in[2];
    const float* b1 = (const float*)d_in[3];
    const float* W2 = (const float*)d_in[4];
    const float* b2 = (const float*)d_in[5];
    const float* W3 = (const float*)d_in[6];
    const float* b3 = (const float*)d_in[7];
    const float* W4 = (const float*)d_in[8];
    const float* b4 = (const float*)d_in[9];
    float* out = (float*)d_out;

    // ws layout: y | z | cnt/cursor | off | srcSorted   (~58.5 MB)
    float* bufA = (float*)d_ws;
    float* bufB = bufA + (size_t)N_NODES * 64;
    int*   cnt  = (int*)(bufB + (size_t)N_NODES * 64);
    int*   off  = cnt + N_NODES;
    int*   srcS = off + N_NODES + 1;

    const int edgeBlocks = (N_EDGES + 255) / 256;     // 6250
    const int mmBlocks   = N_NODES / 16;              // 6250
    const int aggBlocks  = (N_NODES + 3) / 4;         // 25000
    const int tailBlocks = (N_NODES + 255) / 256;     // 391

    // CSR build (once per launch, used by both convs)
    k_zero<<<(N_NODES + 1023) / 1024, 1024, 0, stream>>>(cnt);
    k_count<<<edgeBlocks, 256, 0, stream>>>(ei, cnt);
    k_scan<<<1, 1024, 0, stream>>>(cnt, off);
    k_permute<<<edgeBlocks, 256, 0, stream>>>(ei, cnt, srcS);

    // conv1: y1 = x@W1 ; z1 = y1 + gather-sum(y1)
    k_mm1<<<mmBlocks, 256, 0, stream>>>(x, W1, bufA);
    k_gather_agg<<<aggBlocks, 256, 0, stream>>>(off, srcS, bufA, bufB);
    // conv2: y2 = relu(z1+b1)@W2 ; z2 = y2 + gather-sum(y2)
    k_relu_mm2<<<mmBlocks, 256, 0, stream>>>(bufB, b1, W2, bufA);
    k_gather_agg<<<aggBlocks, 256, 0, stream>>>(off, srcS, bufA, bufB);
    // head
    k_tail<<<tailBlocks, 256, 0, stream>>>(bufB, b2, W3, b3, W4, b4, out);
}

// Round 3
// 466.837 us; speedup vs baseline: 6.2088x; 1.2810x over previous
//
#include <hip/hip_runtime.h>

#define N_NODES 100000
#define N_EDGES 1600000
#define NGROUPS 8
#define NODES_PER_GROUP 12500   // N_NODES / NGROUPS
#define SCAN_BLOCKS 25          // 25 * 4096 = 102400 >= N_NODES

// ---------------------------------------------------------------------------
// CSR build (rebuilt every launch; ws is re-poisoned between calls).
// ---------------------------------------------------------------------------
__global__ __launch_bounds__(1024) void k_zero(int* __restrict__ cnt) {
    int i = blockIdx.x * 1024 + threadIdx.x;
    if (i < N_NODES) cnt[i] = 0;
}

__global__ __launch_bounds__(256) void k_count(const int* __restrict__ ei,
                                               int* __restrict__ cnt) {
    int e = blockIdx.x * 256 + threadIdx.x;
    if (e < N_EDGES) atomicAdd(&cnt[ei[N_EDGES + e]], 1);
}

// Hierarchical scan, stage 1: each block scans a 4096-elem chunk (4/thread),
// writes chunk-local EXCLUSIVE scan to off[] and its chunk total to bsum[].
__global__ __launch_bounds__(1024) void k_scan_local(const int* __restrict__ cnt,
                                                     int* __restrict__ off,
                                                     int* __restrict__ bsum) {
    __shared__ int waveSums[16];
    const int tid  = threadIdx.x;
    const int lane = tid & 63;
    const int wid  = tid >> 6;
    const int base = blockIdx.x * 4096 + tid * 4;
    int v0 = 0, v1 = 0, v2 = 0, v3 = 0;
    const bool inR = (base < N_NODES);          // N_NODES % 4 == 0: all-or-none
    if (inR) { int4 q = *(const int4*)&cnt[base]; v0 = q.x; v1 = q.y; v2 = q.z; v3 = q.w; }
    int s = v0 + v1 + v2 + v3;
    int incl = s;
    #pragma unroll
    for (int d = 1; d < 64; d <<= 1) {
        int n = __shfl_up(incl, d, 64);
        if (lane >= d) incl += n;
    }
    if (lane == 63) waveSums[wid] = incl;
    __syncthreads();
    int waveOff = 0, total = 0;
    #pragma unroll
    for (int w = 0; w < 16; ++w) {
        int ws = waveSums[w];
        waveOff += (w < wid) ? ws : 0;
        total   += ws;
    }
    if (inR) {
        int e0 = waveOff + incl - s;            // chunk-local exclusive
        int4 o = {e0, e0 + v0, e0 + v0 + v1, e0 + v0 + v1 + v2};
        *(int4*)&off[base] = o;
    }
    if (tid == 0) bsum[blockIdx.x] = total;
}

// Stage 2: add chunk base (redundant mini-scan of bsum per block), finalize
// off[] and copy to cnt[] as permute cursors. off[N_NODES] is the known total.
__global__ __launch_bounds__(1024) void k_scan_fix(int* __restrict__ off,
                                                   int* __restrict__ cnt,
                                                   const int* __restrict__ bsum) {
    const int b = blockIdx.x;
    int add = 0;
    for (int j = 0; j < b; ++j) add += bsum[j];
    const int base = b * 4096 + threadIdx.x * 4;
    if (base < N_NODES) {
        int4 q = *(int4*)&off[base];
        q.x += add; q.y += add; q.z += add; q.w += add;
        *(int4*)&off[base] = q;
        *(int4*)&cnt[base] = q;
    }
    if (b == 0 && threadIdx.x == 0) off[N_NODES] = N_EDGES;
}

// XCD-partitioned permute: group g = blockIdx&7 (round-robin block->XCD
// heuristic) handles only dst in its 12500-node range, so each group's srcS
// writes land in one contiguous 1/8 slice (~0.8 MB, L2-resident, written
// back once). 8x redundant dst reads are coalesced + LLC-absorbed.
__global__ __launch_bounds__(256) void k_permute(const int* __restrict__ ei,
                                                 int* __restrict__ cursor,
                                                 int* __restrict__ srcS) {
    const int g     = blockIdx.x & 7;
    const int slice = blockIdx.x >> 3;
    const int lo    = g * NODES_PER_GROUP;
    const int hi    = lo + NODES_PER_GROUP;
    const int e0    = slice * 1280;             // 1250 slices * 1280 = 1.6M exact
    #pragma unroll
    for (int i = 0; i < 5; ++i) {
        int e   = e0 + i * 256 + threadIdx.x;
        int dst = ei[N_EDGES + e];
        if (dst >= lo && dst < hi) {
            int src = ei[e];
            int pos = atomicAdd(&cursor[dst], 1);
            srcS[pos] = src;
        }
    }
}

// ---------------------------------------------------------------------------
// Gather-aggregate: z[n] = y[n] + sum_{e: dst==n} y[src_e].  One wave per
// node, lane == channel (64 ch). No atomics.
// ---------------------------------------------------------------------------
__global__ __launch_bounds__(256) void k_gather_agg(const int* __restrict__ off,
                                                    const int* __restrict__ srcS,
                                                    const float* __restrict__ y,
                                                    float* __restrict__ z) {
    const int node = blockIdx.x * 4 + (threadIdx.x >> 6);
    if (node >= N_NODES) return;
    const int lane = threadIdx.x & 63;
    const int beg = off[node];
    const int end = off[node + 1];
    float acc = y[(size_t)node * 64 + lane];
    int i = beg;
    for (; i + 4 <= end; i += 4) {
        int s0 = srcS[i], s1 = srcS[i + 1], s2 = srcS[i + 2], s3 = srcS[i + 3];
        float v0 = y[(size_t)s0 * 64 + lane];
        float v1 = y[(size_t)s1 * 64 + lane];
        float v2 = y[(size_t)s2 * 64 + lane];
        float v3 = y[(size_t)s3 * 64 + lane];
        acc += (v0 + v1) + (v2 + v3);
    }
    for (; i < end; ++i) acc += y[(size_t)srcS[i] * 64 + lane];
    z[(size_t)node * 64 + lane] = acc;
}

// ---------------------------------------------------------------------------
// K1: y = x @ W1  (N x 128 @ 128 x 64).
// ---------------------------------------------------------------------------
__global__ __launch_bounds__(256) void k_mm1(const float* __restrict__ x,
                                             const float* __restrict__ W1,
                                             float* __restrict__ y) {
    __shared__ float sW[128 * 64];   // 32 KB
    __shared__ float sx[16 * 132];
    const int tid = threadIdx.x;
    for (int i = tid * 4; i < 128 * 64; i += 1024)
        *(float4*)&sW[i] = *(const float4*)&W1[i];
    const int row0 = blockIdx.x * 16;
    for (int i = tid * 4; i < 16 * 128; i += 1024) {
        int r = i >> 7, c = i & 127;
        *(float4*)&sx[r * 132 + c] = *(const float4*)&x[(size_t)(row0 + r) * 128 + c];
    }
    __syncthreads();
    const int r  = tid >> 4;
    const int c4 = (tid & 15) * 4;
    float4 acc = {0.f, 0.f, 0.f, 0.f};
    #pragma unroll 16
    for (int k = 0; k < 128; ++k) {
        float  xv = sx[r * 132 + k];
        float4 w  = *(float4*)&sW[k * 64 + c4];
        acc.x += xv * w.x; acc.y += xv * w.y; acc.z += xv * w.z; acc.w += xv * w.w;
    }
    *(float4*)&y[(size_t)(row0 + r) * 64 + c4] = acc;
}

// ---------------------------------------------------------------------------
// K3: h1 = relu(z1 + b1);  y2 = h1 @ W2  (64x64).
// ---------------------------------------------------------------------------
__global__ __launch_bounds__(256) void k_relu_mm2(const float* __restrict__ z1,
                                                  const float* __restrict__ b1,
                                                  const float* __restrict__ W2,
                                                  float* __restrict__ y2) {
    __shared__ float sW[64 * 64];
    __shared__ float sh[16 * 68];
    const int tid = threadIdx.x;
    for (int i = tid * 4; i < 64 * 64; i += 1024)
        *(float4*)&sW[i] = *(const float4*)&W2[i];
    const int row0 = blockIdx.x * 16;
    {
        int i = tid * 4;
        int r = i >> 6, c = i & 63;
        float4 v  = *(const float4*)&z1[(size_t)(row0 + r) * 64 + c];
        float4 bb = *(const float4*)&b1[c];
        v.x = fmaxf(v.x + bb.x, 0.f);
        v.y = fmaxf(v.y + bb.y, 0.f);
        v.z = fmaxf(v.z + bb.z, 0.f);
        v.w = fmaxf(v.w + bb.w, 0.f);
        *(float4*)&sh[r * 68 + c] = v;
    }
    __syncthreads();
    const int r  = tid >> 4;
    const int c4 = (tid & 15) * 4;
    float4 acc = {0.f, 0.f, 0.f, 0.f};
    #pragma unroll 16
    for (int k = 0; k < 64; ++k) {
        float  hv = sh[r * 68 + k];
        float4 w  = *(float4*)&sW[k * 64 + c4];
        acc.x += hv * w.x; acc.y += hv * w.y; acc.z += hv * w.z; acc.w += hv * w.w;
    }
    *(float4*)&y2[(size_t)(row0 + r) * 64 + c4] = acc;
}

// ---------------------------------------------------------------------------
// K5: per-node tail: h2 = relu(z2+b2); h3 = relu(h2@W3+b3); out = h3@W4+b4.
// ---------------------------------------------------------------------------
__global__ __launch_bounds__(256) void k_tail(const float* __restrict__ z2,
                                              const float* __restrict__ b2,
                                              const float* __restrict__ W3,
                                              const float* __restrict__ b3,
                                              const float* __restrict__ W4,
                                              const float* __restrict__ b4,
                                              float* __restrict__ out) {
    __shared__ float sW3[64 * 16];
    __shared__ float sW4[16];
    __shared__ float sb3[16];
    const int tid = threadIdx.x;
    *(float4*)&sW3[tid * 4] = *(const float4*)&W3[tid * 4];
    if (tid < 16) { sW4[tid] = W4[tid]; sb3[tid] = b3[tid]; }
    __syncthreads();
    const int node = blockIdx.x * 256 + tid;
    if (node >= N_NODES) return;

    float h[64];
    const float4* zp = (const float4*)&z2[(size_t)node * 64];
    #pragma unroll
    for (int i = 0; i < 16; ++i) {
        float4 v  = zp[i];
        float4 bb = *(const float4*)&b2[i * 4];
        h[i * 4 + 0] = fmaxf(v.x + bb.x, 0.f);
        h[i * 4 + 1] = fmaxf(v.y + bb.y, 0.f);
        h[i * 4 + 2] = fmaxf(v.z + bb.z, 0.f);
        h[i * 4 + 3] = fmaxf(v.w + bb.w, 0.f);
    }
    float acc[16];
    #pragma unroll
    for (int j = 0; j < 16; ++j) acc[j] = sb3[j];
    #pragma unroll 8
    for (int k = 0; k < 64; ++k) {
        float hv = h[k];
        #pragma unroll
        for (int j = 0; j < 16; ++j) acc[j] += hv * sW3[k * 16 + j];
    }
    float o = b4[0];
    #pragma unroll
    for (int j = 0; j < 16; ++j) o += fmaxf(acc[j], 0.f) * sW4[j];
    out[node] = o;
}

extern "C" void kernel_launch(void* const* d_in, const int* in_sizes, int n_in,
                              void* d_out, int out_size, void* d_ws, size_t ws_size,
                              hipStream_t stream) {
    const float* x  = (const float*)d_in[0];
    const int*   ei = (const int*)d_in[1];
    const float* W1 = (const float*)d_in[2];
    const float* b1 = (const float*)d_in[3];
    const float* W2 = (const float*)d_in[4];
    const float* b2 = (const float*)d_in[5];
    const float* W3 = (const float*)d_in[6];
    const float* b3 = (const float*)d_in[7];
    const float* W4 = (const float*)d_in[8];
    const float* b4 = (const float*)d_in[9];
    float* out = (float*)d_out;

    // ws layout: y | z | cnt/cursor | off | srcSorted | bsum
    float* bufA = (float*)d_ws;
    float* bufB = bufA + (size_t)N_NODES * 64;
    int*   cnt  = (int*)(bufB + (size_t)N_NODES * 64);
    int*   off  = cnt + N_NODES;
    int*   srcS = off + N_NODES + 4;          // keep 16B alignment slack
    int*   bsum = srcS + N_EDGES;

    const int edgeBlocks = (N_EDGES + 255) / 256;     // 6250
    const int permBlocks = 1250 * NGROUPS;            // 10000
    const int mmBlocks   = N_NODES / 16;              // 6250
    const int aggBlocks  = (N_NODES + 3) / 4;         // 25000
    const int tailBlocks = (N_NODES + 255) / 256;     // 391

    // CSR build (once per launch, used by both convs)
    k_zero<<<(N_NODES + 1023) / 1024, 1024, 0, stream>>>(cnt);
    k_count<<<edgeBlocks, 256, 0, stream>>>(ei, cnt);
    k_scan_local<<<SCAN_BLOCKS, 1024, 0, stream>>>(cnt, off, bsum);
    k_scan_fix<<<SCAN_BLOCKS, 1024, 0, stream>>>(off, cnt, bsum);
    k_permute<<<permBlocks, 256, 0, stream>>>(ei, cnt, srcS);

    // conv1: y1 = x@W1 ; z1 = y1 + gather-sum(y1)
    k_mm1<<<mmBlocks, 256, 0, stream>>>(x, W1, bufA);
    k_gather_agg<<<aggBlocks, 256, 0, stream>>>(off, srcS, bufA, bufB);
    // conv2: y2 = relu(z1+b1)@W2 ; z2 = y2 + gather-sum(y2)
    k_relu_mm2<<<mmBlocks, 256, 0, stream>>>(bufB, b1, W2, bufA);
    k_gather_agg<<<aggBlocks, 256, 0, stream>>>(off, srcS, bufA, bufB);
    // head
    k_tail<<<tailBlocks, 256, 0, stream>>>(bufB, b2, W3, b3, W4, b4, out);
}